// Round 9
// baseline (72489.343 us; speedup 1.0000x reference)
//
#include <hip/hip_runtime.h>
#include <cstdint>

#define TPB 256
#define GRID_WGS 256

// problem dims
#define NB    32
#define TIN   400
#define TOUT  500
#define NMEL  80
#define EDIM  512
#define ARNN  1024
#define PDIM  256
#define ADIM  128
#define NGATE 4096

#define KSA 7        // attention-LSTM K = 1792 = 7 x 256
#define KSD 8        // decoder-LSTM   K = 2560 = 8 x 320
// K1 task split (NO weight duplication): A = 32 jt(128 rows) x 7 ks = 224;
// D = 32 x 8 = 256; total 480 blocks (~2/CU), each 128 j x 32 b x kspan.
#define K1_GRID 480

// double-region offsets (units: doubles)
#define PM_OFF   0          // pmT[b][a][t] [32][128][400]
#define WFC_OFF  1638400    // [128][62]
#define AH_OFF   1646336
#define AC_OFF   1679104
#define DH_OFF   1711872
#define DC_OFF   1744640
#define CTX_OFF  1777408
#define AW_OFF   1793792
#define AWC_OFF  1806592
#define EN_OFF   1819392
#define PQ_OFF   1832192
#define PRE0_OFF 1836288
#define PRE1_OFF 1844480
#define DBL_END  1852672
// float region (units: floats, base = (float*)(ws + DBL_END))
#define PAF_OFF  0          // A partials [7][32][4096]
#define PDF_OFF  917504     // D partials [8][32][4096]
#define WQT_OFF  1966080    // WqT[h][a]  [1024][128]
#define WPGT_OFF 2097152    // WpgT[m][o] [1536][81] (o=80 is gate row)
#define WPGT_LEN 124416
#define F_END    2221568
#define BAR_UINTS 320
#define WS_BYTES ((size_t)DBL_END*8 + (size_t)F_END*4 + (size_t)BAR_UINTS*4)

#define MEL_OFF  0
#define GATE_OFF 1280000
#define AL_OFF   1296000

// ---------------- threefry2x32 core (bit-exact JAX) ----------------
__device__ __forceinline__ uint32_t rotl32(uint32_t v, int r){ return (v<<r)|(v>>(32-r)); }

__device__ __forceinline__ void tf_block(uint32_t k0, uint32_t k1, uint32_t x0, uint32_t x1,
                                         uint32_t& y0, uint32_t& y1){
  uint32_t k2 = k0 ^ k1 ^ 0x1BD11BDAu;
  x0 += k0; x1 += k1;
#define TF4(r0,r1,r2,r3,ka,kb,inc) \
  x0 += x1; x1 = rotl32(x1,r0); x1 ^= x0; \
  x0 += x1; x1 = rotl32(x1,r1); x1 ^= x0; \
  x0 += x1; x1 = rotl32(x1,r2); x1 ^= x0; \
  x0 += x1; x1 = rotl32(x1,r3); x1 ^= x0; \
  x0 += (ka); x1 += (kb) + (inc);
  TF4(13,15,26,6,  k1,k2,1u)
  TF4(17,29,16,24, k2,k0,2u)
  TF4(13,15,26,6,  k0,k1,3u)
  TF4(17,29,16,24, k1,k2,4u)
  TF4(13,15,26,6,  k2,k0,5u)
#undef TF4
  y0 = x0; y1 = x1;
}

__device__ __forceinline__ bool tf_keep_part(uint32_t k0, uint32_t k1, uint32_t i){
  uint32_t y0, y1;
  tf_block(k0, k1, 0u, i, y0, y1);
  return (((y0 ^ y1) >> 31) == 0u);
}

// ---------------- precompute kernels ----------------
__global__ __launch_bounds__(TPB) void pm_kernel(
    const float* __restrict__ memory, const float* __restrict__ Wm, double* __restrict__ pmT)
{
  const int bt = blockIdx.x;           // b*400 + t
  const int b = bt / TIN, t2 = bt - b*TIN;
  const int tid = threadIdx.x;
  __shared__ double sm[EDIM];
  __shared__ double sp[TPB];
  for (int i = tid; i < EDIM; i += TPB) sm[i] = (double)memory[(size_t)bt*EDIM + i];
  __syncthreads();
  const int a = tid & 127, hf = tid >> 7;
  const float* w = Wm + (size_t)a*EDIM + hf*256;
  const double* x = sm + hf*256;
  double s = 0.0;
  for (int e = 0; e < 256; ++e) s += (double)w[e]*x[e];
  sp[tid] = s;
  __syncthreads();
  if (tid < ADIM) pmT[((size_t)b*ADIM + tid)*TIN + t2] = sp[tid] + sp[tid+128];
}

__global__ __launch_bounds__(TPB) void wfc_kernel(
    const float* __restrict__ Wd, const float* __restrict__ Wc, double* __restrict__ wfc)
{
  for (int o = threadIdx.x; o < ADIM*62; o += TPB){
    int a = o / 62, ck = o - a*62;
    double s = 0.0;
    for (int f = 0; f < 32; ++f) s += (double)Wd[a*32+f]*(double)Wc[f*62 + ck];
    wfc[o] = s;
  }
}

// WqT[h*128 + a] = Wq[a*1024 + h]
__global__ __launch_bounds__(TPB) void wqt_kernel(const float* __restrict__ Wq, float* __restrict__ WqT){
  const int a = blockIdx.x;            // 0..127
  for (int h = threadIdx.x; h < ARNN; h += TPB)
    WqT[(size_t)h*ADIM + a] = Wq[(size_t)a*ARNN + h];
}

// WpgT[m*81 + o] = (o<80) ? Wp[o*1536 + m] : Wg[m]
__global__ __launch_bounds__(TPB) void wpgt_kernel(const float* __restrict__ Wp,
                                                   const float* __restrict__ Wg,
                                                   float* __restrict__ WpgT){
  for (int i = blockIdx.x*TPB + threadIdx.x; i < WPGT_LEN; i += 64*TPB){
    const int m = i / 81, o = i - m*81;
    WpgT[i] = (o < 80) ? Wp[(size_t)o*1536 + m] : Wg[m];
  }
}

__global__ __launch_bounds__(TPB) void zero_kernel(double* ws){
  for (size_t i = (size_t)blockIdx.x*TPB + threadIdx.x; i < (size_t)(DBL_END - AH_OFF);
       i += (size_t)GRID_WGS*TPB)
    ws[AH_OFF + i] = 0.0;
}

__global__ void sentinel_kernel(float* out, float val){ out[0] = val; }

// ---------------- params ----------------
struct DecParams {
  const float *memory, *dec;
  const float *Wpre1, *Wpre2;
  const float *WihA,*WhhA,*bihA,*bhhA;
  const float *Wq,*v;
  const float *WihD,*WhhD,*bihD,*bhhD;
  const float *Wp,*bp,*Wg,*bg;
  const unsigned char* mask;
  double* ws;
  float* out;
};

__device__ __forceinline__ double sigd(double x){ return 1.0/(1.0+exp(-x)); }

// 2 outputs x 8 k fp64 FMA block (w0?,w1? scalars must be in scope)
#define ROW2FMA(a0,a1, xp) do{ \
  const double x0=(xp)[0],x1=(xp)[1],x2=(xp)[2],x3=(xp)[3], \
               x4=(xp)[4],x5=(xp)[5],x6=(xp)[6],x7=(xp)[7]; \
  a0 += w00*x0+w01*x1+w02*x2+w03*x3+w04*x4+w05*x5+w06*x6+w07*x7; \
  a1 += w10*x0+w11*x1+w12*x2+w13*x3+w14*x4+w15*x5+w16*x6+w17*x7; \
}while(0)

// ---------------- K1: gate-GEMM partials (A for t, D for t-1) --------------------------
// 480 blocks, 2/CU. Weights staged through LDS per 32-k chunk: cooperative coalesced
// load (8 lanes = one 128B row-line -> 8 lines/wave-inst vs 64 for row-per-lane), and
// the tile is loaded ONCE per block (not once per wave). Lane jg owns rows {jg, 64+jg};
// stride-33 LDS padding puts both at bank (jg+k)%32 -> 2-way conflict (free, m136).
// LDS 48.9 KB -> 2 blocks/CU still fits (unlike the R6 persistent-kernel attempt).
__global__ __launch_bounds__(TPB, 2) void k1_gemm(DecParams P, int t)
{
  const int task = blockIdx.x, tid = threadIdx.x;
  const bool isA = task < 224;
  if (isA ? (t >= TOUT) : (t == 0)) return;
  __shared__ __align__(16) double sbX[4096];      // 32 KB: X[32 b][128 k]
  __shared__ __align__(16) float  wlds[128*33];   // 16.5 KB: W chunk [128 rows][32k+pad]

  double* ws = P.ws;
  const double* pre_cur = ws + ((t & 1) ? PRE1_OFF : PRE0_OFF);
  const double* ctx = ws + CTX_OFF;
  const double* ah  = ws + AH_OFF;
  const double* dh  = ws + DH_OFF;
  float* pAf = (float*)(ws + DBL_END);
  float* pDf = pAf + PDF_OFF;

  int jt, ks, kbase;
  if (isA){ jt = task / KSA; ks = task - jt*KSA; kbase = ks*256; }
  else    { const int q = task-224; jt = q >> 3; ks = q & 7; kbase = ks*320; }
  const int jg = tid & 63, bgi = tid >> 6;
  const int r0 = tid >> 3;            // 0..31: row for coop W load
  const int kq = (tid & 7) << 2;      // 0,4,...,28: float4 k-offset for coop W load
  double acc[16];
  #pragma unroll
  for (int i = 0; i < 16; ++i) acc[i] = 0.0;

  const int npieces = isA ? 2 : 3;
  #pragma unroll 1
  for (int pc = 0; pc < npieces; ++pc){
    const int pb  = kbase + pc*128;
    const int len = (isA || pc < 2) ? 128 : 64;
    // stage X[32 b][len k] into sbX[b*128 + kloc]
    for (int i = tid; i < NB*len; i += TPB){
      int b, kloc;
      if (len == 128){ b = i >> 7; kloc = i & 127; }
      else           { b = i >> 6; kloc = i & 63; }
      const int kg = pb + kloc;
      double xv;
      if (isA){
        if (kg < 256)       xv = pre_cur[(b<<8) + kg];
        else if (kg < 768)  xv = ctx[b*EDIM + (kg-256)];
        else                xv = ah[b*ARNN + (kg-768)];
      } else {
        if (kg < 1024)      xv = ah[b*ARNN + kg];
        else if (kg < 1536) xv = ctx[b*EDIM + (kg-1024)];
        else                xv = dh[b*ARNN + (kg-1536)];
      }
      sbX[(b<<7) + kloc] = xv;
    }
    // piece weight base (pieces never straddle the ih/hh boundary)
    const float* wbase; int rowlen, koff0;
    if (isA){
      if (pb < 768){ wbase = P.WihA; rowlen = 768;  koff0 = pb; }
      else         { wbase = P.WhhA; rowlen = 1024; koff0 = pb-768; }
    } else {
      if (pb < 1536){ wbase = P.WihD; rowlen = 1536; koff0 = pb; }
      else          { wbase = P.WhhD; rowlen = 1024; koff0 = pb-1536; }
    }
    const int nchunks = len >> 5;
    #pragma unroll 1
    for (int c = 0; c < nchunks; ++c){
      const int koff = koff0 + c*32;
      // issue the coop W loads to registers EARLY (hide HBM under prev chunk's FMA)
      const float* wt = wbase + (size_t)(jt*128 + r0)*rowlen + koff + kq;
      const float4 wv0 = *(const float4*)(wt);
      const float4 wv1 = *(const float4*)(wt + (size_t)32*rowlen);
      const float4 wv2 = *(const float4*)(wt + (size_t)64*rowlen);
      const float4 wv3 = *(const float4*)(wt + (size_t)96*rowlen);
      __syncthreads();   // prev chunk's FMA done reading wlds (and X staged, for c==0)
      {
        float* p0 = wlds + (r0     )*33 + kq;
        float* p1 = wlds + (r0 + 32)*33 + kq;
        float* p2 = wlds + (r0 + 64)*33 + kq;
        float* p3 = wlds + (r0 + 96)*33 + kq;
        p0[0]=wv0.x; p0[1]=wv0.y; p0[2]=wv0.z; p0[3]=wv0.w;
        p1[0]=wv1.x; p1[1]=wv1.y; p1[2]=wv1.z; p1[3]=wv1.w;
        p2[0]=wv2.x; p2[1]=wv2.y; p2[2]=wv2.z; p2[3]=wv2.w;
        p3[0]=wv3.x; p3[1]=wv3.y; p3[2]=wv3.z; p3[3]=wv3.w;
      }
      __syncthreads();   // wlds ready
      const int xbase = c*32;
      #pragma unroll
      for (int kk = 0; kk < 32; kk += 8){
        const float* wl0 = wlds + jg*33 + kk;
        const float* wl1 = wlds + (64+jg)*33 + kk;
        const double w00=wl0[0],w01=wl0[1],w02=wl0[2],w03=wl0[3],
                     w04=wl0[4],w05=wl0[5],w06=wl0[6],w07=wl0[7];
        const double w10=wl1[0],w11=wl1[1],w12=wl1[2],w13=wl1[3],
                     w14=wl1[4],w15=wl1[5],w16=wl1[6],w17=wl1[7];
        const double* xb = sbX + xbase + kk;
        #pragma unroll
        for (int bi = 0; bi < 8; ++bi){
          const double* xp = xb + (((bgi<<3)+bi)<<7);
          ROW2FMA(acc[bi*2+0], acc[bi*2+1], xp);
        }
      }
    }
    __syncthreads();   // all FMA done reading sbX before the next piece restages it
  }

  // store partials: rows jg and 64+jg -> consecutive lanes, consecutive floats
  float* pbase = (isA ? pAf : pDf) + ((size_t)ks*NB)*NGATE;
  #pragma unroll
  for (int bi = 0; bi < 8; ++bi){
    const int b = (bgi<<3) + bi;
    float* pp = pbase + (size_t)b*NGATE + jt*128 + jg;
    pp[0]  = (float)acc[bi*2+0];
    pp[64] = (float)acc[bi*2+1];
  }
}

// ---------------- K2: LSTM reduce + activations (+ pq) + prenet(t+1) ------------------
__global__ __launch_bounds__(TPB) void k2_reduce(DecParams P, int t)
{
  const int wg = blockIdx.x, tid = threadIdx.x;
  __shared__ double sb[1536];
  double* ws = P.ws;
  double* ah  = ws + AH_OFF;   double* ac  = ws + AC_OFF;
  double* dh  = ws + DH_OFF;   double* dc  = ws + DC_OFF;
  double* pq  = ws + PQ_OFF;
  float*  pAf = (float*)(ws + DBL_END);
  float*  pDf = pAf + PDF_OFF;
  const float* WqT = pAf + WQT_OFF;

  if (wg < NB){
    if (t < TOUT){
      const int b = wg;
      for (int h = tid; h < ARNN; h += TPB){
        double g0 = (double)P.bihA[h]      + (double)P.bhhA[h];
        double g1 = (double)P.bihA[1024+h] + (double)P.bhhA[1024+h];
        double g2 = (double)P.bihA[2048+h] + (double)P.bhhA[2048+h];
        double g3 = (double)P.bihA[3072+h] + (double)P.bhhA[3072+h];
        for (int p2 = 0; p2 < KSA; ++p2){
          const float* pp = pAf + ((size_t)p2*NB + b)*NGATE;
          g0 += (double)pp[h];        g1 += (double)pp[1024+h];
          g2 += (double)pp[2048+h];   g3 += (double)pp[3072+h];
        }
        const double cp = ac[b*ARNN + h];
        const double cn = sigd(g1)*cp + sigd(g0)*tanh(g2);
        const double hn = sigd(g3)*tanh(cn);
        ac[b*ARNN+h] = cn; ah[b*ARNN+h] = hn; sb[h] = hn;
      }
      __syncthreads();
      {
        const int a2 = tid >> 1, hf = tid & 1;
        const float* wqt = WqT + (size_t)(hf*512)*ADIM + a2;
        const double* xh = sb + hf*512;
        double s = 0.0;
        for (int h2 = 0; h2 < 512; ++h2) s += (double)wqt[(size_t)h2*ADIM]*xh[h2];
        sb[1024 + tid] = s;
      }
      __syncthreads();
      if (tid < ADIM) pq[b*ADIM + tid] = sb[1024 + 2*tid] + sb[1024 + 2*tid + 1];
    }
  } else if (wg < 2*NB){
    if (t > 0){
      const int b = wg - NB;
      for (int h = tid; h < ARNN; h += TPB){
        double g0 = (double)P.bihD[h]      + (double)P.bhhD[h];
        double g1 = (double)P.bihD[1024+h] + (double)P.bhhD[1024+h];
        double g2 = (double)P.bihD[2048+h] + (double)P.bhhD[2048+h];
        double g3 = (double)P.bihD[3072+h] + (double)P.bhhD[3072+h];
        for (int p2 = 0; p2 < KSD; ++p2){
          const float* pp = pDf + ((size_t)p2*NB + b)*NGATE;
          g0 += (double)pp[h];        g1 += (double)pp[1024+h];
          g2 += (double)pp[2048+h];   g3 += (double)pp[3072+h];
        }
        const double cp = dc[b*ARNN + h];
        const double cn = sigd(g1)*cp + sigd(g0)*tanh(g2);
        const double hn = sigd(g3)*tanh(cn);
        dc[b*ARNN+h] = cn; dh[b*ARNN+h] = hn;
      }
    }
  } else {
    if (t < TOUT-1){
      const int b = wg - 2*NB, t1 = t + 1;
      double* pre_next = ws + ((t1 & 1) ? PRE1_OFF : PRE0_OFF);
      for (int m = tid; m < NMEL; m += TPB)
        sb[m] = (double)P.dec[((size_t)b*NMEL + m)*TOUT + (t1-1)];
      __syncthreads();
      uint32_t d1k0, d1k1, d2k0, d2k1;
      tf_block(0u, 42u, 0u, 0u, d1k0, d1k1);
      tf_block(0u, 42u, 0u, 1u, d2k0, d2k1);
      const uint32_t flat = ((uint32_t)(t1*NB + b))*PDIM + tid;
      {
        const float* w = P.Wpre1 + tid*NMEL;
        double s = 0.0;
        for (int m = 0; m < NMEL; ++m) s += sb[m]*(double)w[m];
        double hv = tf_keep_part(d1k0, d1k1, flat) ? s*2.0 : 0.0;
        sb[128 + tid] = fmax(hv, 0.0);
      }
      __syncthreads();
      {
        const float* w = P.Wpre2 + tid*PDIM;
        double s = 0.0;
        for (int m = 0; m < PDIM; ++m) s += sb[128+m]*(double)w[m];
        double pv = tf_keep_part(d2k0, d2k1, flat) ? s*2.0 : 0.0;
        pre_next[(b<<8) + tid] = fmax(pv, 0.0);
      }
    }
  }
}

// ---------------- K3: attention energies (t) + mel/gate (t-1) -------------------------
__global__ __launch_bounds__(TPB) void k3_att(DecParams P, int t)
{
  const int wg = blockIdx.x, tid = threadIdx.x;
  __shared__ double sb[1856];
  double* ws = P.ws;
  double* pmT = ws + PM_OFF;   double* wfc = ws + WFC_OFF;
  double* dh  = ws + DH_OFF;   double* ctx = ws + CTX_OFF;
  double* aw  = ws + AW_OFF;   double* awc = ws + AWC_OFF;
  double* en  = ws + EN_OFF;   double* pq  = ws + PQ_OFF;
  const float* WpgT = (float*)(ws + DBL_END) + WPGT_OFF;

  if (wg < 224){
    if (t < TOUT){
      const int b = wg / 7, tt = wg - b*7;
      const int tbase = tt*64;
      if (tid < ADIM) sb[tid] = pq[b*ADIM + tid];
      for (int i = tid; i < 94; i += TPB){
        int tg = tbase - 15 + i;
        sb[128 + i] = (tg >= 0 && tg < TIN) ? aw[b*TIN + tg] : 0.0;
      }
      for (int i = tid; i < 94; i += TPB){
        int tg = tbase - 15 + i;
        sb[222 + i] = (tg >= 0 && tg < TIN) ? awc[b*TIN + tg] : 0.0;
      }
      __syncthreads();
      const int wv = tid >> 6, lane = tid & 63;
      const int tg = tbase + lane;
      double esum = 0.0;
      if (tg < TIN){
        double w0r[31], w1r[31];
        #pragma unroll
        for (int k = 0; k < 31; ++k){ w0r[k] = sb[128 + lane + k]; w1r[k] = sb[222 + lane + k]; }
        const double* pmrow = pmT + (size_t)b*ADIM*TIN + tg;
        for (int a2 = wv*32; a2 < wv*32 + 32; ++a2){
          const double* wf = wfc + a2*62;
          double cv = 0.0;
          #pragma unroll
          for (int k = 0; k < 31; ++k) cv += wf[k]*w0r[k];
          #pragma unroll
          for (int k = 0; k < 31; ++k) cv += wf[31+k]*w1r[k];
          const double e = sb[a2] + cv + pmrow[(size_t)a2*TIN];
          esum += (double)P.v[a2]*tanh(e);
        }
      }
      sb[640 + wv*64 + lane] = esum;
      __syncthreads();
      if (tid < 64){
        const int tg2 = tbase + tid;
        if (tg2 < TIN){
          double e = sb[640+tid] + sb[704+tid] + sb[768+tid] + sb[832+tid];
          if (P.mask[b*TIN + tg2]) e = -1e9;
          en[b*TIN + tg2] = e;
        }
      }
    }
  } else {
    if (t > 0){
      const int b = wg - 224, ts = t-1;
      for (int i = tid; i < 1536; i += TPB)
        sb[i] = (i < 1024) ? dh[b*ARNN + i] : ctx[b*EDIM + (i-1024)];
      __syncthreads();
      const int o = tid >> 1, hf = tid & 1;
      double s = 0.0;
      if (o <= 80){
        const float* wpt = WpgT + (size_t)(hf*768)*81 + o;
        const double* xr = sb + hf*768;
        for (int m2 = 0; m2 < 768; ++m2) s += (double)wpt[(size_t)m2*81]*xr[m2];
      }
      sb[1600 + tid] = s;
      __syncthreads();
      if (tid <= 80){
        double val = sb[1600 + 2*tid] + sb[1600 + 2*tid + 1];
        if (tid < 80) P.out[MEL_OFF + ((size_t)b*NMEL + tid)*TOUT + ts] = (float)(val + (double)P.bp[tid]);
        else          P.out[GATE_OFF + (size_t)b*TOUT + ts] = (float)(val + (double)P.bg[0]);
      }
    }
  }
}

// ---------------- K4: softmax (redundant x8) + ctx slice on 256 blocks ----------------
__global__ __launch_bounds__(TPB) void k4_ctx(DecParams P, int t)
{
  if (t >= TOUT) return;
  const int wg = blockIdx.x, tid = threadIdx.x;
  __shared__ double sb[1280];
  double* ws = P.ws;
  double* ctx = ws + CTX_OFF;  double* aw  = ws + AW_OFF;  double* awc = ws + AWC_OFF;
  double* en  = ws + EN_OFF;

  const int b = wg >> 3, s = wg & 7;
  double m = -1.0e300;
  for (int i = tid; i < TIN; i += TPB){
    double e = en[b*TIN + i];
    sb[512 + i] = e;
    m = fmax(m, e);
  }
  sb[tid] = m; __syncthreads();
  for (int s2 = TPB/2; s2 > 0; s2 >>= 1){
    if (tid < s2) sb[tid] = fmax(sb[tid], sb[tid+s2]);
    __syncthreads();
  }
  const double mx = sb[0];
  __syncthreads();
  double ssum = 0.0;
  for (int i = tid; i < TIN; i += TPB){
    double u = exp(sb[512+i] - mx);
    sb[512 + i] = u; ssum += u;
  }
  sb[tid] = ssum; __syncthreads();
  for (int s2 = TPB/2; s2 > 0; s2 >>= 1){
    if (tid < s2) sb[tid] += sb[tid+s2];
    __syncthreads();
  }
  const double tot = sb[0];
  __syncthreads();
  for (int i = tid; i < TIN; i += TPB){
    double a2 = sb[512+i] / tot;
    sb[512+i] = a2;
    if (s == 0){
      aw[b*TIN+i] = a2;
      awc[b*TIN+i] += a2;
      P.out[AL_OFF + ((size_t)b*TOUT + t)*TIN + i] = (float)a2;
    }
  }
  __syncthreads();
  {
    const int e2 = s*64 + (tid & 63);
    const int tc = tid >> 6;                     // 0..3 -> t-chunks of 100
    const float* mcol = P.memory + (size_t)b*TIN*EDIM + e2;
    double sacc = 0.0;
    for (int t2 = tc*100; t2 < tc*100 + 100; ++t2)
      sacc += sb[512+t2] * (double)mcol[(size_t)t2*EDIM];
    sb[1024 + tid] = sacc;
    __syncthreads();
    if (tid < 64){
      double v4 = sb[1024+tid] + sb[1088+tid] + sb[1152+tid] + sb[1216+tid];
      ctx[b*EDIM + s*64 + tid] = v4;
    }
  }
}

extern "C" void kernel_launch(void* const* d_in, const int* in_sizes, int n_in,
                              void* d_out, int out_size, void* d_ws, size_t ws_size,
                              hipStream_t stream)
{
  const float* memory = (const float*)d_in[0];
  const float* dec    = (const float*)d_in[1];
  const unsigned char* mask = (const unsigned char*)d_in[2];
  const float* W_pre1 = (const float*)d_in[3];
  const float* W_pre2 = (const float*)d_in[4];
  const float* WihA   = (const float*)d_in[5];
  const float* WhhA   = (const float*)d_in[6];
  const float* bihA   = (const float*)d_in[7];
  const float* bhhA   = (const float*)d_in[8];
  const float* Wq     = (const float*)d_in[9];
  const float* Wm     = (const float*)d_in[10];
  const float* v      = (const float*)d_in[11];
  const float* Wc     = (const float*)d_in[12];
  const float* Wd     = (const float*)d_in[13];
  const float* WihD   = (const float*)d_in[14];
  const float* WhhD   = (const float*)d_in[15];
  const float* bihD   = (const float*)d_in[16];
  const float* bhhD   = (const float*)d_in[17];
  const float* Wp     = (const float*)d_in[18];
  const float* bp     = (const float*)d_in[19];
  const float* Wg     = (const float*)d_in[20];
  const float* bg     = (const float*)d_in[21];

  double* ws = (double*)d_ws;
  float* out = (float*)d_out;

  if (ws_size < WS_BYTES){
    sentinel_kernel<<<1, 1, 0, stream>>>(out, 12345.0f);   // diagnostic: ws too small
    return;
  }

  zero_kernel<<<GRID_WGS, TPB, 0, stream>>>(ws);
  pm_kernel<<<NB*TIN, TPB, 0, stream>>>(memory, Wm, ws + PM_OFF);
  wfc_kernel<<<1, TPB, 0, stream>>>(Wd, Wc, ws + WFC_OFF);
  {
    float* fbase = (float*)(ws + DBL_END);
    wqt_kernel<<<ADIM, TPB, 0, stream>>>(Wq, fbase + WQT_OFF);
    wpgt_kernel<<<64, TPB, 0, stream>>>(Wp, Wg, fbase + WPGT_OFF);
  }

  DecParams P;
  P.memory = memory; P.dec = dec;
  P.Wpre1 = W_pre1; P.Wpre2 = W_pre2;
  P.WihA = WihA; P.WhhA = WhhA; P.bihA = bihA; P.bhhA = bhhA;
  P.Wq = Wq; P.v = v;
  P.WihD = WihD; P.WhhD = WhhD; P.bihD = bihD; P.bhhD = bhhD;
  P.Wp = Wp; P.bp = bp; P.Wg = Wg; P.bg = bg;
  P.mask = mask; P.ws = ws; P.out = out;

  for (int t = 0; t <= TOUT; ++t){
    k1_gemm<<<K1_GRID, TPB, 0, stream>>>(P, t);
    k2_reduce<<<3*NB, TPB, 0, stream>>>(P, t);
    k3_att<<<256, TPB, 0, stream>>>(P, t);
    if (t < TOUT) k4_ctx<<<256, TPB, 0, stream>>>(P, t);
  }
}